// Round 1
// baseline (6217.612 us; speedup 1.0000x reference)
//
#include <hip/hip_runtime.h>

#define NN 131072
#define NE 2097152
#define DD 128
#define LL 3

// ---------------- setup kernels ----------------
__global__ __launch_bounds__(256) void k_init(float* __restrict__ deg,
                                              float* __restrict__ bns) {
    int i = blockIdx.x * 256 + threadIdx.x;
    if (i < NN) deg[i] = 1.0f;          // self-loop contribution
    if (i < 768) bns[i] = 0.0f;         // 3 layers x (sum[128] + sumsq[128])
}

__global__ __launch_bounds__(256) void k_deg(const int* __restrict__ tgt,
                                             float* __restrict__ deg) {
    int e = blockIdx.x * 256 + threadIdx.x;   // grid exact: NE/256
    atomicAdd(&deg[tgt[e]], 1.0f);
}

__global__ __launch_bounds__(256) void k_rsqrt(float* __restrict__ d) {
    int i = blockIdx.x * 256 + threadIdx.x;
    d[i] = rsqrtf(d[i]);                // deg >= 1 always (self-loop)
}

// ---------------- GEMM: C[N,128] = A[N,K] @ W[K,128] ----------------
// 32 rows/block, 256 threads, 4x4 microtile. A tile staged row-major in LDS,
// a-values read via broadcast (2 distinct addrs/wave -> conflict-free).
template <int K>
__global__ __launch_bounds__(256) void k_gemm(const float* __restrict__ A,
                                              const float* __restrict__ W,
                                              float* __restrict__ C) {
    __shared__ float As[32][K + 1];
    const int t = threadIdx.x;
    const int row0 = blockIdx.x * 32;
    for (int idx = t; idx < 32 * K; idx += 256) {
        int r = idx / K, k = idx - r * K;
        As[r][k] = A[(size_t)(row0 + r) * K + k];
    }
    __syncthreads();
    const int tc = (t & 31) * 4;
    const int tr = (t >> 5) * 4;
    float acc[4][4] = {};
#pragma unroll 4
    for (int k = 0; k < K; ++k) {
        const float4 b = *reinterpret_cast<const float4*>(&W[k * DD + tc]);
#pragma unroll
        for (int j = 0; j < 4; ++j) {
            float a = As[tr + j][k];
            acc[j][0] += a * b.x; acc[j][1] += a * b.y;
            acc[j][2] += a * b.z; acc[j][3] += a * b.w;
        }
    }
#pragma unroll
    for (int j = 0; j < 4; ++j) {
        float4 v = make_float4(acc[j][0], acc[j][1], acc[j][2], acc[j][3]);
        *reinterpret_cast<float4*>(&C[(size_t)(row0 + tr + j) * DD + tc]) = v;
    }
}

// ---------------- fused residual GEMM + BN + ReLU ----------------
// H = relu(conv*scale + shift) + H @ Wres + bres   (in-place on H: each block
// stages its own 32 rows into LDS before any write -> safe)
__global__ __launch_bounds__(256) void k_gemm_fused(
    float* __restrict__ H, const float* __restrict__ Wres,
    const float* __restrict__ bres, const float* __restrict__ conv,
    const float* __restrict__ ss) {
    __shared__ float As[32][DD + 1];
    const int t = threadIdx.x;
    const int row0 = blockIdx.x * 32;
    for (int idx = t; idx < 32 * DD; idx += 256) {
        int r = idx >> 7, k = idx & 127;
        As[r][k] = H[(size_t)(row0 + r) * DD + k];
    }
    __syncthreads();
    const int tc = (t & 31) * 4;
    const int tr = (t >> 5) * 4;
    float acc[4][4] = {};
#pragma unroll 4
    for (int k = 0; k < DD; ++k) {
        const float4 b = *reinterpret_cast<const float4*>(&Wres[k * DD + tc]);
#pragma unroll
        for (int j = 0; j < 4; ++j) {
            float a = As[tr + j][k];
            acc[j][0] += a * b.x; acc[j][1] += a * b.y;
            acc[j][2] += a * b.z; acc[j][3] += a * b.w;
        }
    }
    const float4 sc = *reinterpret_cast<const float4*>(&ss[tc]);
    const float4 sh = *reinterpret_cast<const float4*>(&ss[DD + tc]);
    const float4 bb = *reinterpret_cast<const float4*>(&bres[tc]);
#pragma unroll
    for (int j = 0; j < 4; ++j) {
        const float4 cv =
            *reinterpret_cast<const float4*>(&conv[(size_t)(row0 + tr + j) * DD + tc]);
        float4 v;
        v.x = acc[j][0] + bb.x + fmaxf(cv.x * sc.x + sh.x, 0.0f);
        v.y = acc[j][1] + bb.y + fmaxf(cv.y * sc.y + sh.y, 0.0f);
        v.z = acc[j][2] + bb.z + fmaxf(cv.z * sc.z + sh.z, 0.0f);
        v.w = acc[j][3] + bb.w + fmaxf(cv.w * sc.w + sh.w, 0.0f);
        *reinterpret_cast<float4*>(&H[(size_t)(row0 + tr + j) * DD + tc]) = v;
    }
}

// ---------------- conv init with self-loop term ----------------
__global__ __launch_bounds__(256) void k_selfloop(const float* __restrict__ hW,
                                                  const float* __restrict__ dinv,
                                                  float* __restrict__ conv) {
    size_t i = (size_t)blockIdx.x * 256 + threadIdx.x;  // over NN*32 float4s
    int node = (int)(i >> 5);
    float di = dinv[node];
    di = di * di;
    float4 v = reinterpret_cast<const float4*>(hW)[i];
    v.x *= di; v.y *= di; v.z *= di; v.w *= di;
    reinterpret_cast<float4*>(conv)[i] = v;
}

// ---------------- edge scatter: conv[tgt] += norm * hW[src] ----------------
__global__ __launch_bounds__(256) void k_scatter(const int* __restrict__ src,
                                                 const int* __restrict__ tgt,
                                                 const float* __restrict__ dinv,
                                                 const float* __restrict__ hW,
                                                 float* __restrict__ out) {
    const int e = blockIdx.x * 4 + (threadIdx.x >> 6);   // grid exact: NE/4
    const int lane = threadIdx.x & 63;
    const int s = src[e], d = tgt[e];
    const float nrm = dinv[s] * dinv[d];
    const float2 v =
        *reinterpret_cast<const float2*>(&hW[(size_t)s * DD + lane * 2]);
    float* o = &out[(size_t)d * DD + lane * 2];
    atomicAdd(o, nrm * v.x);
    atomicAdd(o + 1, nrm * v.y);
}

// ---------------- BN statistics ----------------
__global__ __launch_bounds__(256) void k_bnstats(const float* __restrict__ conv,
                                                 float* __restrict__ sums) {
    const int c = threadIdx.x & 127;
    const int half = threadIdx.x >> 7;
    const int r0 = blockIdx.x * 1024;    // grid = NN/1024
    float s = 0.0f, s2 = 0.0f;
    for (int r = r0 + half; r < r0 + 1024; r += 2) {
        float v = conv[(size_t)r * DD + c];
        s += v; s2 += v * v;
    }
    atomicAdd(&sums[c], s);
    atomicAdd(&sums[DD + c], s2);
}

__global__ void k_bnfin(const float* __restrict__ sums,
                        const float* __restrict__ gamma,
                        const float* __restrict__ beta,
                        float* __restrict__ ss) {
    int c = threadIdx.x;   // 128 threads
    const float invN = 1.0f / (float)NN;
    float mean = sums[c] * invN;
    float var = sums[DD + c] * invN - mean * mean;
    float sc = gamma[c] * rsqrtf(var + 1e-5f);
    ss[c] = sc;
    ss[DD + c] = beta[c] - mean * sc;
}

// ---------------- launch ----------------
extern "C" void kernel_launch(void* const* d_in, const int* in_sizes, int n_in,
                              void* d_out, int out_size, void* d_ws, size_t ws_size,
                              hipStream_t stream) {
    const float* x      = (const float*)d_in[0];
    const int*   ei     = (const int*)d_in[1];
    const float* W_init = (const float*)d_in[3];
    const float* W_gcn  = (const float*)d_in[4];
    const float* gamma  = (const float*)d_in[6];
    const float* beta   = (const float*)d_in[7];
    const float* W_res  = (const float*)d_in[8];
    const float* b_res  = (const float*)d_in[9];

    float* h    = (float*)d_out;                 // h lives in d_out
    float* ws   = (float*)d_ws;
    float* hW   = ws;                            // NN*128
    float* conv = ws + (size_t)NN * DD;          // NN*128
    float* dinv = conv + (size_t)NN * DD;        // NN
    float* bns  = dinv + NN;                     // 768
    float* ss   = bns + 768;                     // 256

    const int* srcp = ei;
    const int* tgtp = ei + NE;

    k_init<<<NN / 256, 256, 0, stream>>>(dinv, bns);
    k_deg<<<NE / 256, 256, 0, stream>>>(tgtp, dinv);
    k_rsqrt<<<NN / 256, 256, 0, stream>>>(dinv);

    k_gemm<74><<<NN / 32, 256, 0, stream>>>(x, W_init, h);

    for (int i = 0; i < LL; ++i) {
        k_gemm<128><<<NN / 32, 256, 0, stream>>>(h, W_gcn + (size_t)i * DD * DD, hW);
        k_selfloop<<<NN * 32 / 256, 256, 0, stream>>>(hW, dinv, conv);
        k_scatter<<<NE / 4, 256, 0, stream>>>(srcp, tgtp, dinv, hW, conv);
        k_bnstats<<<NN / 1024, 256, 0, stream>>>(conv, bns + i * 256);
        k_bnfin<<<1, 128, 0, stream>>>(bns + i * 256, gamma + i * DD,
                                       beta + i * DD, ss);
        k_gemm_fused<<<NN / 32, 256, 0, stream>>>(h, W_res + (size_t)i * DD * DD,
                                                  b_res + i * DD, conv, ss);
    }
}

// Round 2
// 1561.900 us; speedup vs baseline: 3.9808x; 3.9808x over previous
//
#include <hip/hip_runtime.h>

#define NN 131072
#define NE 2097152
#define DD 128
#define LL 3

// ---------------- CSR build ----------------
__global__ __launch_bounds__(256) void k_zero(int* __restrict__ counts,
                                              float* __restrict__ bns) {
    int i = blockIdx.x * 256 + threadIdx.x;
    if (i < NN) counts[i] = 0;
    if (i < 768) bns[i] = 0.0f;   // 3 layers x (sum[128] + sumsq[128])
}

__global__ __launch_bounds__(256) void k_count(const int* __restrict__ tgt,
                                               int* __restrict__ counts) {
    int e = blockIdx.x * 256 + threadIdx.x;   // grid exact: NE/256
    atomicAdd(&counts[tgt[e]], 1);
}

__global__ __launch_bounds__(256) void k_dinv(const int* __restrict__ counts,
                                              float* __restrict__ dinv) {
    int i = blockIdx.x * 256 + threadIdx.x;
    dinv[i] = rsqrtf((float)(counts[i] + 1));   // +1 self-loop
}

// single-block exclusive scan over NN counts -> row offsets + cursor copy
__global__ __launch_bounds__(1024) void k_scan(const int* __restrict__ counts,
                                               int* __restrict__ row,
                                               int* __restrict__ cursor) {
    __shared__ int part[1024];
    const int t = threadIdx.x;
    const int base = t * 128;
    int s = 0;
    for (int j = 0; j < 128; ++j) s += counts[base + j];
    part[t] = s;
    __syncthreads();
    for (int off = 1; off < 1024; off <<= 1) {
        int v = part[t];
        int u = (t >= off) ? part[t - off] : 0;
        __syncthreads();
        part[t] = v + u;
        __syncthreads();
    }
    int run = (t == 0) ? 0 : part[t - 1];
    for (int j = 0; j < 128; ++j) {
        int c = counts[base + j];
        row[base + j] = run;
        cursor[base + j] = run;
        run += c;
    }
    if (t == 1023) row[NN] = run;
}

__global__ __launch_bounds__(256) void k_fill(const int* __restrict__ src,
                                              const int* __restrict__ tgt,
                                              int* __restrict__ cursor,
                                              int* __restrict__ ssrc) {
    int e = blockIdx.x * 256 + threadIdx.x;
    int pos = atomicAdd(&cursor[tgt[e]], 1);
    ssrc[pos] = src[e];
}

// ---------------- GEMM: C[N,128] = A[N,K] @ W[K,128] ----------------
template <int K>
__global__ __launch_bounds__(256) void k_gemm(const float* __restrict__ A,
                                              const float* __restrict__ W,
                                              float* __restrict__ C) {
    __shared__ float As[32][K + 1];
    const int t = threadIdx.x;
    const int row0 = blockIdx.x * 32;
    for (int idx = t; idx < 32 * K; idx += 256) {
        int r = idx / K, k = idx - r * K;
        As[r][k] = A[(size_t)(row0 + r) * K + k];
    }
    __syncthreads();
    const int tc = (t & 31) * 4;
    const int tr = (t >> 5) * 4;
    float acc[4][4] = {};
#pragma unroll 4
    for (int k = 0; k < K; ++k) {
        const float4 b = *reinterpret_cast<const float4*>(&W[k * DD + tc]);
#pragma unroll
        for (int j = 0; j < 4; ++j) {
            float a = As[tr + j][k];
            acc[j][0] += a * b.x; acc[j][1] += a * b.y;
            acc[j][2] += a * b.z; acc[j][3] += a * b.w;
        }
    }
#pragma unroll
    for (int j = 0; j < 4; ++j) {
        float4 v = make_float4(acc[j][0], acc[j][1], acc[j][2], acc[j][3]);
        *reinterpret_cast<float4*>(&C[(size_t)(row0 + tr + j) * DD + tc]) = v;
    }
}

// ---------------- fused residual GEMM + BN + ReLU ----------------
__global__ __launch_bounds__(256) void k_gemm_fused(
    float* __restrict__ H, const float* __restrict__ Wres,
    const float* __restrict__ bres, const float* __restrict__ conv,
    const float* __restrict__ ss) {
    __shared__ float As[32][DD + 1];
    const int t = threadIdx.x;
    const int row0 = blockIdx.x * 32;
    for (int idx = t; idx < 32 * DD; idx += 256) {
        int r = idx >> 7, k = idx & 127;
        As[r][k] = H[(size_t)(row0 + r) * DD + k];
    }
    __syncthreads();
    const int tc = (t & 31) * 4;
    const int tr = (t >> 5) * 4;
    float acc[4][4] = {};
#pragma unroll 4
    for (int k = 0; k < DD; ++k) {
        const float4 b = *reinterpret_cast<const float4*>(&Wres[k * DD + tc]);
#pragma unroll
        for (int j = 0; j < 4; ++j) {
            float a = As[tr + j][k];
            acc[j][0] += a * b.x; acc[j][1] += a * b.y;
            acc[j][2] += a * b.z; acc[j][3] += a * b.w;
        }
    }
    const float4 sc = *reinterpret_cast<const float4*>(&ss[tc]);
    const float4 sh = *reinterpret_cast<const float4*>(&ss[DD + tc]);
    const float4 bb = *reinterpret_cast<const float4*>(&bres[tc]);
#pragma unroll
    for (int j = 0; j < 4; ++j) {
        const float4 cv =
            *reinterpret_cast<const float4*>(&conv[(size_t)(row0 + tr + j) * DD + tc]);
        float4 v;
        v.x = acc[j][0] + bb.x + fmaxf(cv.x * sc.x + sh.x, 0.0f);
        v.y = acc[j][1] + bb.y + fmaxf(cv.y * sc.y + sh.y, 0.0f);
        v.z = acc[j][2] + bb.z + fmaxf(cv.z * sc.z + sh.z, 0.0f);
        v.w = acc[j][3] + bb.w + fmaxf(cv.w * sc.w + sh.w, 0.0f);
        *reinterpret_cast<float4*>(&H[(size_t)(row0 + tr + j) * DD + tc]) = v;
    }
}

// ---------------- CSR aggregate: conv[n] = dinv[n]^2*hW[n] + sum nrm*hW[s] ----
__global__ __launch_bounds__(256) void k_aggregate(const int* __restrict__ row,
                                                   const int* __restrict__ ssrc,
                                                   const float* __restrict__ dinv,
                                                   const float* __restrict__ hW,
                                                   float* __restrict__ conv) {
    const int n = blockIdx.x * 4 + (threadIdx.x >> 6);   // grid exact: NN/4
    const int lane = threadIdx.x & 63;
    const float dn = dinv[n];
    float2 acc = *reinterpret_cast<const float2*>(&hW[(size_t)n * DD + lane * 2]);
    const float dn2 = dn * dn;
    acc.x *= dn2; acc.y *= dn2;
    const int e0 = row[n], e1 = row[n + 1];
    for (int base = e0; base < e1; base += 64) {
        const int cnt = min(64, e1 - base);
        int sv = 0;
        float dv = 0.0f;
        if (lane < cnt) {
            sv = ssrc[base + lane];
            dv = dinv[sv];
        }
        for (int i = 0; i < cnt; ++i) {
            const int s = __shfl(sv, i);
            const float nrm = dn * __shfl(dv, i);
            const float2 v =
                *reinterpret_cast<const float2*>(&hW[(size_t)s * DD + lane * 2]);
            acc.x += nrm * v.x;
            acc.y += nrm * v.y;
        }
    }
    *reinterpret_cast<float2*>(&conv[(size_t)n * DD + lane * 2]) = acc;
}

// ---------------- BN statistics ----------------
__global__ __launch_bounds__(256) void k_bnstats(const float* __restrict__ conv,
                                                 float* __restrict__ sums) {
    const int c = threadIdx.x & 127;
    const int half = threadIdx.x >> 7;
    const int r0 = blockIdx.x * 256;    // grid = NN/256
    float s = 0.0f, s2 = 0.0f;
    for (int r = r0 + half; r < r0 + 256; r += 2) {
        float v = conv[(size_t)r * DD + c];
        s += v; s2 += v * v;
    }
    atomicAdd(&sums[c], s);
    atomicAdd(&sums[DD + c], s2);
}

__global__ void k_bnfin(const float* __restrict__ sums,
                        const float* __restrict__ gamma,
                        const float* __restrict__ beta,
                        float* __restrict__ ss) {
    int c = threadIdx.x;   // 128 threads
    const float invN = 1.0f / (float)NN;
    float mean = sums[c] * invN;
    float var = sums[DD + c] * invN - mean * mean;
    float sc = gamma[c] * rsqrtf(var + 1e-5f);
    ss[c] = sc;
    ss[DD + c] = beta[c] - mean * sc;
}

// ---------------- launch ----------------
extern "C" void kernel_launch(void* const* d_in, const int* in_sizes, int n_in,
                              void* d_out, int out_size, void* d_ws, size_t ws_size,
                              hipStream_t stream) {
    const float* x      = (const float*)d_in[0];
    const int*   ei     = (const int*)d_in[1];
    const float* W_init = (const float*)d_in[3];
    const float* W_gcn  = (const float*)d_in[4];
    const float* gamma  = (const float*)d_in[6];
    const float* beta   = (const float*)d_in[7];
    const float* W_res  = (const float*)d_in[8];
    const float* b_res  = (const float*)d_in[9];

    float* h    = (float*)d_out;                 // h lives in d_out
    float* ws   = (float*)d_ws;
    float* hW   = ws;                            // NN*128 f32
    float* conv = hW + (size_t)NN * DD;          // NN*128 f32
    float* dinv = conv + (size_t)NN * DD;        // NN f32
    float* bns  = dinv + NN;                     // 768
    float* ss   = bns + 768;                     // 256
    int* counts = (int*)(ss + 256);              // NN i32
    int* rowp   = counts + NN;                   // NN+1 i32
    int* cursor = rowp + NN + 1;                 // NN i32
    int* ssrc   = cursor + NN;                   // NE i32

    const int* srcp = ei;
    const int* tgtp = ei + NE;

    k_zero<<<NN / 256, 256, 0, stream>>>(counts, bns);
    k_count<<<NE / 256, 256, 0, stream>>>(tgtp, counts);
    k_scan<<<1, 1024, 0, stream>>>(counts, rowp, cursor);
    k_dinv<<<NN / 256, 256, 0, stream>>>(counts, dinv);
    k_fill<<<NE / 256, 256, 0, stream>>>(srcp, tgtp, cursor, ssrc);

    k_gemm<74><<<NN / 32, 256, 0, stream>>>(x, W_init, h);

    for (int i = 0; i < LL; ++i) {
        k_gemm<128><<<NN / 32, 256, 0, stream>>>(h, W_gcn + (size_t)i * DD * DD, hW);
        k_aggregate<<<NN / 4, 256, 0, stream>>>(rowp, ssrc, dinv, hW, conv);
        k_bnstats<<<NN / 256, 256, 0, stream>>>(conv, bns + i * 256);
        k_bnfin<<<1, 128, 0, stream>>>(bns + i * 256, gamma + i * DD,
                                       beta + i * DD, ss);
        k_gemm_fused<<<NN / 32, 256, 0, stream>>>(h, W_res + (size_t)i * DD * DD,
                                                  b_res + i * DD, conv, ss);
    }
}

// Round 3
// 1066.838 us; speedup vs baseline: 5.8281x; 1.4640x over previous
//
#include <hip/hip_runtime.h>

#define NN 131072
#define NE 2097152
#define DD 128
#define LL 3

typedef __attribute__((ext_vector_type(8))) short short8;
typedef __attribute__((ext_vector_type(4))) float f32x4;

__device__ __forceinline__ ushort f2bf(float f) {
    uint u = __float_as_uint(f);
    return (ushort)((u + 0x7fffu + ((u >> 16) & 1u)) >> 16);   // RNE
}
__device__ __forceinline__ float bflo(uint u) { return __uint_as_float(u << 16); }
__device__ __forceinline__ float bfhi(uint u) { return __uint_as_float(u & 0xffff0000u); }

// ---------------- CSR build ----------------
__global__ __launch_bounds__(256) void k_zero(int* __restrict__ counts,
                                              float* __restrict__ bns) {
    int i = blockIdx.x * 256 + threadIdx.x;
    if (i < NN) counts[i] = 0;
    if (i < 768) bns[i] = 0.0f;
}

__global__ __launch_bounds__(256) void k_count(const int* __restrict__ tgt,
                                               int* __restrict__ counts) {
    int e = blockIdx.x * 256 + threadIdx.x;
    atomicAdd(&counts[tgt[e]], 1);
}

__global__ __launch_bounds__(256) void k_dinv(const int* __restrict__ counts,
                                              float* __restrict__ dinv) {
    int i = blockIdx.x * 256 + threadIdx.x;
    dinv[i] = rsqrtf((float)(counts[i] + 1));
}

__global__ __launch_bounds__(1024) void k_scan(const int* __restrict__ counts,
                                               int* __restrict__ row,
                                               int* __restrict__ cursor) {
    __shared__ int part[1024];
    const int t = threadIdx.x;
    const int base = t * 128;
    int s = 0;
    for (int j = 0; j < 128; ++j) s += counts[base + j];
    part[t] = s;
    __syncthreads();
    for (int off = 1; off < 1024; off <<= 1) {
        int v = part[t];
        int u = (t >= off) ? part[t - off] : 0;
        __syncthreads();
        part[t] = v + u;
        __syncthreads();
    }
    int run = (t == 0) ? 0 : part[t - 1];
    for (int j = 0; j < 128; ++j) {
        int c = counts[base + j];
        row[base + j] = run;
        cursor[base + j] = run;
        run += c;
    }
    if (t == 1023) row[NN] = run;
}

__global__ __launch_bounds__(256) void k_fill(const int* __restrict__ src,
                                              const int* __restrict__ tgt,
                                              int* __restrict__ cursor,
                                              int* __restrict__ ssrc) {
    int e = blockIdx.x * 256 + threadIdx.x;
    int pos = atomicAdd(&cursor[tgt[e]], 1);
    ssrc[pos] = src[e];
}

// ---------------- weight transpose+convert: wt[m][c][k] = bf16(W_m[k][c]) ----
__global__ __launch_bounds__(256) void k_prepw(const float* __restrict__ Wi,
                                               const float* __restrict__ Wg,
                                               const float* __restrict__ Wr,
                                               ushort* __restrict__ wt) {
    const int id = blockIdx.x * 256 + threadIdx.x;   // 7*16384
    const int m = id >> 14;
    const int c = (id >> 7) & 127;
    const int k = id & 127;
    float v;
    if (m == 0)      v = (k < 74) ? Wi[k * DD + c] : 0.0f;
    else if (m <= 3) v = Wg[(size_t)(m - 1) * DD * DD + k * DD + c];
    else             v = Wr[(size_t)(m - 4) * DD * DD + k * DD + c];
    wt[id] = f2bf(v);
}

// ---------------- x f32[NN][74] -> bf16[NN][128] zero-padded ----------------
__global__ __launch_bounds__(256) void k_convx(const float* __restrict__ x,
                                               uint* __restrict__ xb) {
    const size_t id = (size_t)blockIdx.x * 256 + threadIdx.x;   // NN*64
    const int n = (int)(id >> 6);
    const int k0 = (int)(id & 63) * 2;
    float v0 = (k0 < 74) ? x[(size_t)n * 74 + k0] : 0.0f;
    float v1 = (k0 + 1 < 74) ? x[(size_t)n * 74 + k0 + 1] : 0.0f;
    xb[id] = (uint)f2bf(v0) | ((uint)f2bf(v1) << 16);
}

// ---------------- MFMA GEMM: out[N,128] = A_bf16[N,128] @ Wt_bf16^T ----------
// MODE 0: outb = bf16(acc)
// MODE 1: outb = bf16(relu(conv*sc+sh) + acc + bres)        (in-place on hb)
// MODE 2: MODE 1 + outf = f32 value (final output)
template <int MODE>
__global__ __launch_bounds__(256) void k_mgemm(const ushort* A,
                                               const ushort* __restrict__ Bt,
                                               ushort* outb,
                                               float* __restrict__ outf,
                                               const float* __restrict__ conv,
                                               const float* __restrict__ ss,
                                               const float* __restrict__ bres) {
    __shared__ ushort As[16384];   // 128 rows x 128 k, XOR-swizzled, 32KB
    __shared__ ushort Bs[16384];
    const int t = threadIdx.x;
    const int w = t >> 6, l = t & 63;
    const int lc = l & 15, lr = l >> 4;
    const size_t row0 = (size_t)blockIdx.x * 128;

    // stage via global_load_lds(16B): linear LDS dest, pre-swizzled source
    for (int ch = w * 8; ch < w * 8 + 8; ++ch) {
        const int row = ch * 4 + lr;
        const int kb = (lc * 16) ^ ((row & 7) << 4);
        const ushort* srcA = A + (row0 + row) * DD + (kb >> 1);
        const ushort* srcB = Bt + (size_t)row * DD + (kb >> 1);
        __builtin_amdgcn_global_load_lds(
            (const __attribute__((address_space(1))) void*)srcA,
            (__attribute__((address_space(3))) void*)(As + ch * 512), 16, 0, 0);
        __builtin_amdgcn_global_load_lds(
            (const __attribute__((address_space(1))) void*)srcB,
            (__attribute__((address_space(3))) void*)(Bs + ch * 512), 16, 0, 0);
    }
    __syncthreads();

    f32x4 acc[2][8] = {};
    const char* Ab = (const char*)As;
    const char* Bb = (const char*)Bs;
#pragma unroll
    for (int kk = 0; kk < 4; ++kk) {
        const int kb = kk * 64 + lr * 16;
        short8 a[2];
#pragma unroll
        for (int m = 0; m < 2; ++m) {
            const int r = w * 32 + m * 16 + lc;
            a[m] = *(const short8*)(Ab + r * 256 + (kb ^ ((r & 7) << 4)));
        }
#pragma unroll
        for (int n = 0; n < 8; ++n) {
            const int c = n * 16 + lc;
            short8 b = *(const short8*)(Bb + c * 256 + (kb ^ ((c & 7) << 4)));
            acc[0][n] = __builtin_amdgcn_mfma_f32_16x16x32_bf16(a[0], b, acc[0][n], 0, 0, 0);
            acc[1][n] = __builtin_amdgcn_mfma_f32_16x16x32_bf16(a[1], b, acc[1][n], 0, 0, 0);
        }
    }

    if (MODE == 0) {
#pragma unroll
        for (int m = 0; m < 2; ++m)
#pragma unroll
            for (int n = 0; n < 8; ++n) {
                const int c = n * 16 + lc;
#pragma unroll
                for (int j = 0; j < 4; ++j) {
                    const size_t r = row0 + w * 32 + m * 16 + lr * 4 + j;
                    outb[r * DD + c] = f2bf(acc[m][n][j]);
                }
            }
    } else {
        float scv[8], shv[8], bbv[8];
#pragma unroll
        for (int n = 0; n < 8; ++n) {
            const int c = n * 16 + lc;
            scv[n] = ss[c]; shv[n] = ss[DD + c]; bbv[n] = bres[c];
        }
#pragma unroll
        for (int m = 0; m < 2; ++m)
#pragma unroll
            for (int n = 0; n < 8; ++n) {
                const int c = n * 16 + lc;
#pragma unroll
                for (int j = 0; j < 4; ++j) {
                    const size_t r = row0 + w * 32 + m * 16 + lr * 4 + j;
                    const float cv = conv[r * DD + c];
                    const float v = fmaxf(cv * scv[n] + shv[n], 0.0f) + acc[m][n][j] + bbv[n];
                    outb[r * DD + c] = f2bf(v);
                    if (MODE == 2) outf[r * DD + c] = v;
                }
            }
    }
}

// ---------------- CSR aggregate (bf16 gather): conv = D^-1/2 A D^-1/2 hW -----
__global__ __launch_bounds__(256) void k_aggregate(const int* __restrict__ row,
                                                   const int* __restrict__ ssrc,
                                                   const float* __restrict__ dinv,
                                                   const uint* __restrict__ hWb,
                                                   float* __restrict__ conv) {
    const int n = blockIdx.x * 4 + (threadIdx.x >> 6);
    const int l = threadIdx.x & 63;
    const float dn = dinv[n];
    const uint u = hWb[(size_t)n * 64 + l];
    const float dn2 = dn * dn;
    float2 acc = make_float2(bflo(u) * dn2, bfhi(u) * dn2);
    const int e0 = row[n], e1 = row[n + 1];
    for (int base = e0; base < e1; base += 64) {
        const int cnt = min(64, e1 - base);
        int sv = 0; float dv = 0.0f;
        if (l < cnt) { sv = ssrc[base + l]; dv = dinv[sv]; }
        for (int i = 0; i < cnt; ++i) {
            const int s = __shfl(sv, i);
            const float nrm = dn * __shfl(dv, i);
            const uint v = hWb[(size_t)s * 64 + l];
            acc.x += nrm * bflo(v);
            acc.y += nrm * bfhi(v);
        }
    }
    *reinterpret_cast<float2*>(&conv[(size_t)n * DD + l * 2]) = acc;
}

// ---------------- BN ----------------
__global__ __launch_bounds__(256) void k_bnstats(const float* __restrict__ conv,
                                                 float* __restrict__ sums) {
    const int c = threadIdx.x & 127;
    const int half = threadIdx.x >> 7;
    const int r0 = blockIdx.x * 256;
    float s = 0.0f, s2 = 0.0f;
    for (int r = r0 + half; r < r0 + 256; r += 2) {
        float v = conv[(size_t)r * DD + c];
        s += v; s2 += v * v;
    }
    atomicAdd(&sums[c], s);
    atomicAdd(&sums[DD + c], s2);
}

__global__ void k_bnfin(const float* __restrict__ sums,
                        const float* __restrict__ gamma,
                        const float* __restrict__ beta,
                        float* __restrict__ ss) {
    int c = threadIdx.x;
    const float invN = 1.0f / (float)NN;
    float mean = sums[c] * invN;
    float var = sums[DD + c] * invN - mean * mean;
    float sc = gamma[c] * rsqrtf(var + 1e-5f);
    ss[c] = sc;
    ss[DD + c] = beta[c] - mean * sc;
}

// ---------------- launch ----------------
extern "C" void kernel_launch(void* const* d_in, const int* in_sizes, int n_in,
                              void* d_out, int out_size, void* d_ws, size_t ws_size,
                              hipStream_t stream) {
    const float* x      = (const float*)d_in[0];
    const int*   ei     = (const int*)d_in[1];
    const float* W_init = (const float*)d_in[3];
    const float* W_gcn  = (const float*)d_in[4];
    const float* gamma  = (const float*)d_in[6];
    const float* beta   = (const float*)d_in[7];
    const float* W_res  = (const float*)d_in[8];
    const float* b_res  = (const float*)d_in[9];

    float* h = (float*)d_out;
    char* p = (char*)d_ws;
    ushort* hWb = (ushort*)p;            p += (size_t)NN * DD * 2;   // 32MB
    ushort* hb  = (ushort*)p;            p += (size_t)NN * DD * 2;   // 32MB
    float*  conv = (float*)p;            p += (size_t)NN * DD * 4;   // 64MB
    uint*   xb   = (uint*)conv;          // aliases conv: dead before first conv write
    float*  dinv = (float*)p;            p += (size_t)NN * 4;
    float*  bns  = (float*)p;            p += 768 * 4;
    float*  ss   = (float*)p;            p += 256 * 4;
    ushort* wt   = (ushort*)p;           p += 7 * 16384 * 2;
    int* counts  = (int*)p;              p += (size_t)NN * 4;
    int* rowp    = (int*)p;              p += ((size_t)NN + 1) * 4 + 4;
    int* cursor  = (int*)p;              p += (size_t)NN * 4;
    int* ssrc    = (int*)p;

    const int* srcp = ei;
    const int* tgtp = ei + NE;

    k_zero<<<NN / 256, 256, 0, stream>>>(counts, bns);
    k_count<<<NE / 256, 256, 0, stream>>>(tgtp, counts);
    k_scan<<<1, 1024, 0, stream>>>(counts, rowp, cursor);
    k_dinv<<<NN / 256, 256, 0, stream>>>(counts, dinv);
    k_fill<<<NE / 256, 256, 0, stream>>>(srcp, tgtp, cursor, ssrc);
    k_prepw<<<7 * 16384 / 256, 256, 0, stream>>>(W_init, W_gcn, W_res, wt);
    k_convx<<<NN * 64 / 256, 256, 0, stream>>>(x, xb);

    k_mgemm<0><<<NN / 128, 256, 0, stream>>>((const ushort*)xb, wt, hb,
                                             nullptr, nullptr, nullptr, nullptr);

    for (int i = 0; i < LL; ++i) {
        k_mgemm<0><<<NN / 128, 256, 0, stream>>>(hb, wt + (size_t)(1 + i) * 16384,
                                                 hWb, nullptr, nullptr, nullptr, nullptr);
        k_aggregate<<<NN / 4, 256, 0, stream>>>(rowp, ssrc, dinv, (const uint*)hWb, conv);
        k_bnstats<<<NN / 256, 256, 0, stream>>>(conv, bns + i * 256);
        k_bnfin<<<1, 128, 0, stream>>>(bns + i * 256, gamma + i * DD,
                                       beta + i * DD, ss);
        if (i < LL - 1)
            k_mgemm<1><<<NN / 128, 256, 0, stream>>>(hb, wt + (size_t)(4 + i) * 16384,
                                                     hb, nullptr, conv, ss, b_res + i * DD);
        else
            k_mgemm<2><<<NN / 128, 256, 0, stream>>>(hb, wt + (size_t)(4 + i) * 16384,
                                                     hb, h, conv, ss, b_res + i * DD);
    }
}

// Round 4
// 836.714 us; speedup vs baseline: 7.4310x; 1.2750x over previous
//
#include <hip/hip_runtime.h>

#define NN 131072
#define NE 2097152
#define DD 128
#define LL 3

#define NB 256      // partition buckets
#define BSH 9       // log2(nodes per bucket) -> 512 nodes/bucket
#define TILE (NE / NB)   // 8192 edges per pass-A block

typedef __attribute__((ext_vector_type(8))) short short8;
typedef __attribute__((ext_vector_type(4))) float f32x4;

__device__ __forceinline__ ushort f2bf(float f) {
    uint u = __float_as_uint(f);
    return (ushort)((u + 0x7fffu + ((u >> 16) & 1u)) >> 16);   // RNE
}
__device__ __forceinline__ float bflo(uint u) { return __uint_as_float(u << 16); }
__device__ __forceinline__ float bfhi(uint u) { return __uint_as_float(u & 0xffff0000u); }

// ---------------- misc init ----------------
__global__ __launch_bounds__(256) void k_zero(float* __restrict__ bns) {
    int i = blockIdx.x * 256 + threadIdx.x;
    if (i < 768) bns[i] = 0.0f;
}

// ---------------- Pass A: bucket histogram per block ----------------
__global__ __launch_bounds__(256) void kA_count(const int* __restrict__ tgt,
                                                int* __restrict__ blockHist) {
    __shared__ int hist[NB];
    const int t = threadIdx.x, blk = blockIdx.x;
    hist[t] = 0;
    __syncthreads();
    const int base = blk * TILE;
#pragma unroll 8
    for (int j = 0; j < TILE / 256; ++j)
        atomicAdd(&hist[tgt[base + j * 256 + t] >> BSH], 1);
    __syncthreads();
    blockHist[t * NB + blk] = hist[t];   // bucket-major
}

// ---------------- Pass A scan: chunk bases (absolute) + bucket starts --------
__global__ __launch_bounds__(256) void kA_scan(int* __restrict__ blockHist,
                                               int* __restrict__ bstart) {
    __shared__ int part[NB];
    const int t = threadIdx.x;
    int4* bh = (int4*)(blockHist + t * NB);
    int run = 0;
    int4 tmp[NB / 4];
#pragma unroll 8
    for (int j = 0; j < NB / 4; ++j) tmp[j] = bh[j];
#pragma unroll 8
    for (int j = 0; j < NB / 4; ++j) {
        int4 v = tmp[j];
        int a = run; run += v.x;
        int b = run; run += v.y;
        int c = run; run += v.z;
        int d = run; run += v.w;
        tmp[j] = make_int4(a, b, c, d);
    }
    part[t] = run;                       // bucket size
    __syncthreads();
    for (int off = 1; off < NB; off <<= 1) {
        int v = part[t];
        int u = (t >= off) ? part[t - off] : 0;
        __syncthreads();
        part[t] = v + u;
        __syncthreads();
    }
    const int excl = part[t] - run;      // exclusive bucket start
    bstart[t] = excl;
    if (t == NB - 1) bstart[NB] = part[t];
#pragma unroll 8
    for (int j = 0; j < NB / 4; ++j) {
        int4 v = tmp[j];
        bh[j] = make_int4(v.x + excl, v.y + excl, v.z + excl, v.w + excl);
    }
}

// ---------------- Pass A scatter: packed = src | tgt_local<<17 ---------------
__global__ __launch_bounds__(256) void kA_scatter(const int* __restrict__ src,
                                                  const int* __restrict__ tgt,
                                                  const int* __restrict__ chunkBase,
                                                  uint* __restrict__ packed) {
    __shared__ int cur[NB];
    const int t = threadIdx.x, blk = blockIdx.x;
    cur[t] = chunkBase[t * NB + blk];
    __syncthreads();
    const int base = blk * TILE;
#pragma unroll 4
    for (int j = 0; j < TILE / 256; ++j) {
        const int e = base + j * 256 + t;
        const int tg = tgt[e], s = src[e];
        const int b = tg >> BSH;
        const int pos = atomicAdd(&cur[b], 1);
        packed[pos] = (uint)s | ((uint)(tg & ((1 << BSH) - 1)) << 17);
    }
}

// ---------------- Pass B: per-bucket counting sort -> rowp, dinv, ssrc -------
__global__ __launch_bounds__(256) void kB_sort(const uint* __restrict__ packed,
                                               const int* __restrict__ bstart,
                                               int* __restrict__ rowp,
                                               float* __restrict__ dinv,
                                               int* __restrict__ ssrc) {
    __shared__ int cnt[1 << BSH];
    __shared__ int pscan[256];
    const int t = threadIdx.x, b = blockIdx.x;
    const int e0 = bstart[b], e1 = bstart[b + 1];
    cnt[t] = 0; cnt[t + 256] = 0;
    __syncthreads();
    for (int e = e0 + t; e < e1; e += 256)
        atomicAdd(&cnt[packed[e] >> 17], 1);
    __syncthreads();
    const int c0 = cnt[2 * t], c1 = cnt[2 * t + 1];
    pscan[t] = c0 + c1;
    __syncthreads();
    for (int off = 1; off < 256; off <<= 1) {
        int v = pscan[t];
        int u = (t >= off) ? pscan[t - off] : 0;
        __syncthreads();
        pscan[t] = v + u;
        __syncthreads();
    }
    const int ex0 = pscan[t] - c0 - c1;
    const int ex1 = ex0 + c0;
    const int n0 = (b << BSH) + 2 * t;
    rowp[n0] = e0 + ex0;
    rowp[n0 + 1] = e0 + ex1;
    dinv[n0] = rsqrtf((float)(c0 + 1));
    dinv[n0 + 1] = rsqrtf((float)(c1 + 1));
    if (b == NB - 1 && t == 255) rowp[NN] = e1;
    __syncthreads();
    cnt[2 * t] = ex0;
    cnt[2 * t + 1] = ex1;
    __syncthreads();
    for (int e = e0 + t; e < e1; e += 256) {
        const uint p = packed[e];
        const int pos = atomicAdd(&cnt[p >> 17], 1);
        ssrc[e0 + pos] = (int)(p & 0x1FFFFu);
    }
}

// ---------------- weight transpose+convert: wt[m][c][k] = bf16(W_m[k][c]) ----
__global__ __launch_bounds__(256) void k_prepw(const float* __restrict__ Wi,
                                               const float* __restrict__ Wg,
                                               const float* __restrict__ Wr,
                                               ushort* __restrict__ wt) {
    const int id = blockIdx.x * 256 + threadIdx.x;   // 7*16384
    const int m = id >> 14;
    const int c = (id >> 7) & 127;
    const int k = id & 127;
    float v;
    if (m == 0)      v = (k < 74) ? Wi[k * DD + c] : 0.0f;
    else if (m <= 3) v = Wg[(size_t)(m - 1) * DD * DD + k * DD + c];
    else             v = Wr[(size_t)(m - 4) * DD * DD + k * DD + c];
    wt[id] = f2bf(v);
}

// ---------------- x f32[NN][74] -> bf16[NN][128] zero-padded ----------------
__global__ __launch_bounds__(256) void k_convx(const float* __restrict__ x,
                                               uint* __restrict__ xb) {
    const size_t id = (size_t)blockIdx.x * 256 + threadIdx.x;   // NN*64
    const int n = (int)(id >> 6);
    const int k0 = (int)(id & 63) * 2;
    float v0 = (k0 < 74) ? x[(size_t)n * 74 + k0] : 0.0f;
    float v1 = (k0 + 1 < 74) ? x[(size_t)n * 74 + k0 + 1] : 0.0f;
    xb[id] = (uint)f2bf(v0) | ((uint)f2bf(v1) << 16);
}

// ---------------- MFMA GEMM: out[N,128] = A_bf16[N,128] @ Wt_bf16^T ----------
// MODE 0: outb = bf16(acc)
// MODE 1: outb = bf16(relu(conv*sc+sh) + acc + bres)        (in-place on hb)
// MODE 2: MODE 1 + outf = f32 value (final output)
template <int MODE>
__global__ __launch_bounds__(256) void k_mgemm(const ushort* A,
                                               const ushort* __restrict__ Bt,
                                               ushort* outb,
                                               float* __restrict__ outf,
                                               const float* __restrict__ conv,
                                               const float* __restrict__ ss,
                                               const float* __restrict__ bres) {
    __shared__ ushort As[16384];   // 128 rows x 128 k, XOR-swizzled, 32KB
    __shared__ ushort Bs[16384];
    const int t = threadIdx.x;
    const int w = t >> 6, l = t & 63;
    const int lc = l & 15, lr = l >> 4;
    const size_t row0 = (size_t)blockIdx.x * 128;

    for (int ch = w * 8; ch < w * 8 + 8; ++ch) {
        const int row = ch * 4 + lr;
        const int kb = (lc * 16) ^ ((row & 7) << 4);
        const ushort* srcA = A + (row0 + row) * DD + (kb >> 1);
        const ushort* srcB = Bt + (size_t)row * DD + (kb >> 1);
        __builtin_amdgcn_global_load_lds(
            (const __attribute__((address_space(1))) void*)srcA,
            (__attribute__((address_space(3))) void*)(As + ch * 512), 16, 0, 0);
        __builtin_amdgcn_global_load_lds(
            (const __attribute__((address_space(1))) void*)srcB,
            (__attribute__((address_space(3))) void*)(Bs + ch * 512), 16, 0, 0);
    }
    __syncthreads();

    f32x4 acc[2][8] = {};
    const char* Ab = (const char*)As;
    const char* Bb = (const char*)Bs;
#pragma unroll
    for (int kk = 0; kk < 4; ++kk) {
        const int kb = kk * 64 + lr * 16;
        short8 a[2];
#pragma unroll
        for (int m = 0; m < 2; ++m) {
            const int r = w * 32 + m * 16 + lc;
            a[m] = *(const short8*)(Ab + r * 256 + (kb ^ ((r & 7) << 4)));
        }
#pragma unroll
        for (int n = 0; n < 8; ++n) {
            const int c = n * 16 + lc;
            short8 b = *(const short8*)(Bb + c * 256 + (kb ^ ((c & 7) << 4)));
            acc[0][n] = __builtin_amdgcn_mfma_f32_16x16x32_bf16(a[0], b, acc[0][n], 0, 0, 0);
            acc[1][n] = __builtin_amdgcn_mfma_f32_16x16x32_bf16(a[1], b, acc[1][n], 0, 0, 0);
        }
    }

    if (MODE == 0) {
#pragma unroll
        for (int m = 0; m < 2; ++m)
#pragma unroll
            for (int n = 0; n < 8; ++n) {
                const int c = n * 16 + lc;
#pragma unroll
                for (int j = 0; j < 4; ++j) {
                    const size_t r = row0 + w * 32 + m * 16 + lr * 4 + j;
                    outb[r * DD + c] = f2bf(acc[m][n][j]);
                }
            }
    } else {
        float scv[8], shv[8], bbv[8];
#pragma unroll
        for (int n = 0; n < 8; ++n) {
            const int c = n * 16 + lc;
            scv[n] = ss[c]; shv[n] = ss[DD + c]; bbv[n] = bres[c];
        }
#pragma unroll
        for (int m = 0; m < 2; ++m)
#pragma unroll
            for (int n = 0; n < 8; ++n) {
                const int c = n * 16 + lc;
#pragma unroll
                for (int j = 0; j < 4; ++j) {
                    const size_t r = row0 + w * 32 + m * 16 + lr * 4 + j;
                    const float cv = conv[r * DD + c];
                    const float v = fmaxf(cv * scv[n] + shv[n], 0.0f) + acc[m][n][j] + bbv[n];
                    outb[r * DD + c] = f2bf(v);
                    if (MODE == 2) outf[r * DD + c] = v;
                }
            }
    }
}

// ---------------- CSR aggregate (bf16 gather): conv = D^-1/2 A D^-1/2 hW -----
__global__ __launch_bounds__(256) void k_aggregate(const int* __restrict__ row,
                                                   const int* __restrict__ ssrc,
                                                   const float* __restrict__ dinv,
                                                   const uint* __restrict__ hWb,
                                                   float* __restrict__ conv) {
    const int n = blockIdx.x * 4 + (threadIdx.x >> 6);
    const int l = threadIdx.x & 63;
    const float dn = dinv[n];
    const uint u = hWb[(size_t)n * 64 + l];
    const float dn2 = dn * dn;
    float2 acc = make_float2(bflo(u) * dn2, bfhi(u) * dn2);
    const int e0 = row[n], e1 = row[n + 1];
    for (int base = e0; base < e1; base += 64) {
        const int cnt = min(64, e1 - base);
        int sv = 0; float dv = 0.0f;
        if (l < cnt) { sv = ssrc[base + l]; dv = dinv[sv]; }
        for (int i = 0; i < cnt; ++i) {
            const int s = __shfl(sv, i);
            const float nrm = dn * __shfl(dv, i);
            const uint v = hWb[(size_t)s * 64 + l];
            acc.x += nrm * bflo(v);
            acc.y += nrm * bfhi(v);
        }
    }
    *reinterpret_cast<float2*>(&conv[(size_t)n * DD + l * 2]) = acc;
}

// ---------------- BN ----------------
__global__ __launch_bounds__(256) void k_bnstats(const float* __restrict__ conv,
                                                 float* __restrict__ sums) {
    const int c = threadIdx.x & 127;
    const int half = threadIdx.x >> 7;
    const int r0 = blockIdx.x * 256;
    float s = 0.0f, s2 = 0.0f;
    for (int r = r0 + half; r < r0 + 256; r += 2) {
        float v = conv[(size_t)r * DD + c];
        s += v; s2 += v * v;
    }
    atomicAdd(&sums[c], s);
    atomicAdd(&sums[DD + c], s2);
}

__global__ void k_bnfin(const float* __restrict__ sums,
                        const float* __restrict__ gamma,
                        const float* __restrict__ beta,
                        float* __restrict__ ss) {
    int c = threadIdx.x;
    const float invN = 1.0f / (float)NN;
    float mean = sums[c] * invN;
    float var = sums[DD + c] * invN - mean * mean;
    float sc = gamma[c] * rsqrtf(var + 1e-5f);
    ss[c] = sc;
    ss[DD + c] = beta[c] - mean * sc;
}

// ---------------- launch ----------------
extern "C" void kernel_launch(void* const* d_in, const int* in_sizes, int n_in,
                              void* d_out, int out_size, void* d_ws, size_t ws_size,
                              hipStream_t stream) {
    const float* x      = (const float*)d_in[0];
    const int*   ei     = (const int*)d_in[1];
    const float* W_init = (const float*)d_in[3];
    const float* W_gcn  = (const float*)d_in[4];
    const float* gamma  = (const float*)d_in[6];
    const float* beta   = (const float*)d_in[7];
    const float* W_res  = (const float*)d_in[8];
    const float* b_res  = (const float*)d_in[9];

    float* h = (float*)d_out;
    char* p = (char*)d_ws;
    ushort* hWb = (ushort*)p;            p += (size_t)NN * DD * 2;   // 32MB
    ushort* hb  = (ushort*)p;            p += (size_t)NN * DD * 2;   // 32MB
    float*  conv = (float*)p;            p += (size_t)NN * DD * 4;   // 64MB
    uint*   xb   = (uint*)conv;          // aliases conv: dead before first conv write
    float*  dinv = (float*)p;            p += (size_t)NN * 4;
    float*  bns  = (float*)p;            p += 768 * 4;
    float*  ss   = (float*)p;            p += 256 * 4;
    ushort* wt   = (ushort*)p;           p += 7 * 16384 * 2;
    int* blockHist = (int*)p;            p += (size_t)NB * NB * 4;
    int* bstart  = (int*)p;              p += (NB + 1) * 4 + 4;
    uint* packed = (uint*)p;             p += (size_t)NE * 4;
    int* rowp    = (int*)p;              p += ((size_t)NN + 1) * 4 + 4;
    int* ssrc    = (int*)p;

    const int* srcp = ei;
    const int* tgtp = ei + NE;

    k_zero<<<3, 256, 0, stream>>>(bns);
    kA_count<<<NB, 256, 0, stream>>>(tgtp, blockHist);
    kA_scan<<<1, 256, 0, stream>>>(blockHist, bstart);
    kA_scatter<<<NB, 256, 0, stream>>>(srcp, tgtp, blockHist, packed);
    kB_sort<<<NB, 256, 0, stream>>>(packed, bstart, rowp, dinv, ssrc);

    k_prepw<<<7 * 16384 / 256, 256, 0, stream>>>(W_init, W_gcn, W_res, wt);
    k_convx<<<NN * 64 / 256, 256, 0, stream>>>(x, xb);

    k_mgemm<0><<<NN / 128, 256, 0, stream>>>((const ushort*)xb, wt, hb,
                                             nullptr, nullptr, nullptr, nullptr);

    for (int i = 0; i < LL; ++i) {
        k_mgemm<0><<<NN / 128, 256, 0, stream>>>(hb, wt + (size_t)(1 + i) * 16384,
                                                 hWb, nullptr, nullptr, nullptr, nullptr);
        k_aggregate<<<NN / 4, 256, 0, stream>>>(rowp, ssrc, dinv, (const uint*)hWb, conv);
        k_bnstats<<<NN / 256, 256, 0, stream>>>(conv, bns + i * 256);
        k_bnfin<<<1, 128, 0, stream>>>(bns + i * 256, gamma + i * DD,
                                       beta + i * DD, ss);
        if (i < LL - 1)
            k_mgemm<1><<<NN / 128, 256, 0, stream>>>(hb, wt + (size_t)(4 + i) * 16384,
                                                     hb, nullptr, conv, ss, b_res + i * DD);
        else
            k_mgemm<2><<<NN / 128, 256, 0, stream>>>(hb, wt + (size_t)(4 + i) * 16384,
                                                     hb, h, conv, ss, b_res + i * DD);
    }
}

// Round 5
// 579.367 us; speedup vs baseline: 10.7317x; 1.4442x over previous
//
#include <hip/hip_runtime.h>

#define NN 131072
#define NE 2097152
#define DD 128
#define LL 3

#define NB 256      // partition buckets
#define BSH 9       // log2(nodes per bucket) -> 512 nodes/bucket
#define TILE (NE / NB)   // 8192 edges per pass-A block

typedef __attribute__((ext_vector_type(8))) short short8;
typedef __attribute__((ext_vector_type(4))) float f32x4;

__device__ __forceinline__ ushort f2bf(float f) {
    uint u = __float_as_uint(f);
    return (ushort)((u + 0x7fffu + ((u >> 16) & 1u)) >> 16);   // RNE
}
__device__ __forceinline__ float bflo(uint u) { return __uint_as_float(u << 16); }
__device__ __forceinline__ float bfhi(uint u) { return __uint_as_float(u & 0xffff0000u); }

// ---------------- misc init ----------------
__global__ __launch_bounds__(256) void k_zero(float* __restrict__ bns) {
    int i = blockIdx.x * 256 + threadIdx.x;
    if (i < 768) bns[i] = 0.0f;
}

// ---------------- Pass A: bucket histogram per block ----------------
__global__ __launch_bounds__(256) void kA_count(const int* __restrict__ tgt,
                                                int* __restrict__ blockHist) {
    __shared__ int hist[NB];
    const int t = threadIdx.x, blk = blockIdx.x;
    hist[t] = 0;
    __syncthreads();
    const int base = blk * TILE;
#pragma unroll 8
    for (int j = 0; j < TILE / 256; ++j)
        atomicAdd(&hist[tgt[base + j * 256 + t] >> BSH], 1);
    __syncthreads();
    blockHist[t * NB + blk] = hist[t];   // bucket-major
}

// ---------------- Pass A scan: chunk bases (absolute) + bucket starts --------
__global__ __launch_bounds__(256) void kA_scan(int* __restrict__ blockHist,
                                               int* __restrict__ bstart) {
    __shared__ int part[NB];
    const int t = threadIdx.x;
    int4* bh = (int4*)(blockHist + t * NB);
    int run = 0;
    int4 tmp[NB / 4];
#pragma unroll 8
    for (int j = 0; j < NB / 4; ++j) tmp[j] = bh[j];
#pragma unroll 8
    for (int j = 0; j < NB / 4; ++j) {
        int4 v = tmp[j];
        int a = run; run += v.x;
        int b = run; run += v.y;
        int c = run; run += v.z;
        int d = run; run += v.w;
        tmp[j] = make_int4(a, b, c, d);
    }
    part[t] = run;                       // bucket size
    __syncthreads();
    for (int off = 1; off < NB; off <<= 1) {
        int v = part[t];
        int u = (t >= off) ? part[t - off] : 0;
        __syncthreads();
        part[t] = v + u;
        __syncthreads();
    }
    const int excl = part[t] - run;      // exclusive bucket start
    bstart[t] = excl;
    if (t == NB - 1) bstart[NB] = part[t];
#pragma unroll 8
    for (int j = 0; j < NB / 4; ++j) {
        int4 v = tmp[j];
        bh[j] = make_int4(v.x + excl, v.y + excl, v.z + excl, v.w + excl);
    }
}

// ---------------- Pass A scatter: packed = src | tgt_local<<17 ---------------
__global__ __launch_bounds__(256) void kA_scatter(const int* __restrict__ src,
                                                  const int* __restrict__ tgt,
                                                  const int* __restrict__ chunkBase,
                                                  uint* __restrict__ packed) {
    __shared__ int cur[NB];
    const int t = threadIdx.x, blk = blockIdx.x;
    cur[t] = chunkBase[t * NB + blk];
    __syncthreads();
    const int base = blk * TILE;
#pragma unroll 4
    for (int j = 0; j < TILE / 256; ++j) {
        const int e = base + j * 256 + t;
        const int tg = tgt[e], s = src[e];
        const int b = tg >> BSH;
        const int pos = atomicAdd(&cur[b], 1);
        packed[pos] = (uint)s | ((uint)(tg & ((1 << BSH) - 1)) << 17);
    }
}

// ---------------- Pass B: per-bucket counting sort -> rowp, dinv, ssrc -------
__global__ __launch_bounds__(256) void kB_sort(const uint* __restrict__ packed,
                                               const int* __restrict__ bstart,
                                               int* __restrict__ rowp,
                                               float* __restrict__ dinv,
                                               int* __restrict__ ssrc) {
    __shared__ int cnt[1 << BSH];
    __shared__ int pscan[256];
    const int t = threadIdx.x, b = blockIdx.x;
    const int e0 = bstart[b], e1 = bstart[b + 1];
    cnt[t] = 0; cnt[t + 256] = 0;
    __syncthreads();
    for (int e = e0 + t; e < e1; e += 256)
        atomicAdd(&cnt[packed[e] >> 17], 1);
    __syncthreads();
    const int c0 = cnt[2 * t], c1 = cnt[2 * t + 1];
    pscan[t] = c0 + c1;
    __syncthreads();
    for (int off = 1; off < 256; off <<= 1) {
        int v = pscan[t];
        int u = (t >= off) ? pscan[t - off] : 0;
        __syncthreads();
        pscan[t] = v + u;
        __syncthreads();
    }
    const int ex0 = pscan[t] - c0 - c1;
    const int ex1 = ex0 + c0;
    const int n0 = (b << BSH) + 2 * t;
    rowp[n0] = e0 + ex0;
    rowp[n0 + 1] = e0 + ex1;
    dinv[n0] = rsqrtf((float)(c0 + 1));
    dinv[n0 + 1] = rsqrtf((float)(c1 + 1));
    if (b == NB - 1 && t == 255) rowp[NN] = e1;
    __syncthreads();
    cnt[2 * t] = ex0;
    cnt[2 * t + 1] = ex1;
    __syncthreads();
    for (int e = e0 + t; e < e1; e += 256) {
        const uint p = packed[e];
        const int pos = atomicAdd(&cnt[p >> 17], 1);
        ssrc[e0 + pos] = (int)(p & 0x1FFFFu);
    }
}

// ---------------- weight transpose+convert: wt[m][c][k] = bf16(W_m[k][c]) ----
__global__ __launch_bounds__(256) void k_prepw(const float* __restrict__ Wi,
                                               const float* __restrict__ Wg,
                                               const float* __restrict__ Wr,
                                               ushort* __restrict__ wt) {
    const int id = blockIdx.x * 256 + threadIdx.x;   // 7*16384
    const int m = id >> 14;
    const int c = (id >> 7) & 127;
    const int k = id & 127;
    float v;
    if (m == 0)      v = (k < 74) ? Wi[k * DD + c] : 0.0f;
    else if (m <= 3) v = Wg[(size_t)(m - 1) * DD * DD + k * DD + c];
    else             v = Wr[(size_t)(m - 4) * DD * DD + k * DD + c];
    wt[id] = f2bf(v);
}

// ---------------- x f32[NN][74] -> bf16[NN][128] zero-padded ----------------
__global__ __launch_bounds__(256) void k_convx(const float* __restrict__ x,
                                               uint* __restrict__ xb) {
    const size_t id = (size_t)blockIdx.x * 256 + threadIdx.x;   // NN*64
    const int n = (int)(id >> 6);
    const int k0 = (int)(id & 63) * 2;
    float v0 = (k0 < 74) ? x[(size_t)n * 74 + k0] : 0.0f;
    float v1 = (k0 + 1 < 74) ? x[(size_t)n * 74 + k0 + 1] : 0.0f;
    xb[id] = (uint)f2bf(v0) | ((uint)f2bf(v1) << 16);
}

// ---------------- MFMA GEMM: [N,128] @ Wt^T ----------------
// MODE 0: outb = bf16(acc)                                   (init transform)
// MODE 1: outf = acc (f32 conv) + column sum/sumsq -> bnsums (GCN gemm)
// MODE 2: outb = bf16(relu(conv*sc+sh) + acc + bres)         (fused residual)
// MODE 3: MODE 2 + outf = f32 value (final output)
template <int MODE>
__global__ __launch_bounds__(256) void k_mgemm(const ushort* A,
                                               const ushort* __restrict__ Bt,
                                               ushort* outb,
                                               float* __restrict__ outf,
                                               const float* __restrict__ conv,
                                               const float* __restrict__ ss,
                                               const float* __restrict__ bres,
                                               float* __restrict__ bnsums) {
    __shared__ ushort As[16384];   // 128 rows x 128 k, XOR-swizzled, 32KB
    __shared__ ushort Bs[16384];
    __shared__ float sred[256];
    const int t = threadIdx.x;
    const int w = t >> 6, l = t & 63;
    const int lc = l & 15, lr = l >> 4;
    const size_t row0 = (size_t)blockIdx.x * 128;

    for (int ch = w * 8; ch < w * 8 + 8; ++ch) {
        const int row = ch * 4 + lr;
        const int kb = (lc * 16) ^ ((row & 7) << 4);
        const ushort* srcA = A + (row0 + row) * DD + (kb >> 1);
        const ushort* srcB = Bt + (size_t)row * DD + (kb >> 1);
        __builtin_amdgcn_global_load_lds(
            (const __attribute__((address_space(1))) void*)srcA,
            (__attribute__((address_space(3))) void*)(As + ch * 512), 16, 0, 0);
        __builtin_amdgcn_global_load_lds(
            (const __attribute__((address_space(1))) void*)srcB,
            (__attribute__((address_space(3))) void*)(Bs + ch * 512), 16, 0, 0);
    }
    if (MODE == 1) sred[t] = 0.0f;
    __syncthreads();

    f32x4 acc[2][8] = {};
    const char* Ab = (const char*)As;
    const char* Bb = (const char*)Bs;
#pragma unroll
    for (int kk = 0; kk < 4; ++kk) {
        const int kb = kk * 64 + lr * 16;
        short8 a[2];
#pragma unroll
        for (int m = 0; m < 2; ++m) {
            const int r = w * 32 + m * 16 + lc;
            a[m] = *(const short8*)(Ab + r * 256 + (kb ^ ((r & 7) << 4)));
        }
#pragma unroll
        for (int n = 0; n < 8; ++n) {
            const int c = n * 16 + lc;
            short8 b = *(const short8*)(Bb + c * 256 + (kb ^ ((c & 7) << 4)));
            acc[0][n] = __builtin_amdgcn_mfma_f32_16x16x32_bf16(a[0], b, acc[0][n], 0, 0, 0);
            acc[1][n] = __builtin_amdgcn_mfma_f32_16x16x32_bf16(a[1], b, acc[1][n], 0, 0, 0);
        }
    }

    if (MODE == 0) {
#pragma unroll
        for (int m = 0; m < 2; ++m)
#pragma unroll
            for (int n = 0; n < 8; ++n) {
                const int c = n * 16 + lc;
#pragma unroll
                for (int j = 0; j < 4; ++j) {
                    const size_t r = row0 + w * 32 + m * 16 + lr * 4 + j;
                    outb[r * DD + c] = f2bf(acc[m][n][j]);
                }
            }
    } else if (MODE == 1) {
#pragma unroll
        for (int n = 0; n < 8; ++n) {
            const int c = n * 16 + lc;
            float ps = 0.0f, ps2 = 0.0f;
#pragma unroll
            for (int m = 0; m < 2; ++m)
#pragma unroll
                for (int j = 0; j < 4; ++j) {
                    const size_t r = row0 + w * 32 + m * 16 + lr * 4 + j;
                    const float v = acc[m][n][j];
                    outf[r * DD + c] = v;
                    ps += v; ps2 += v * v;
                }
            atomicAdd(&sred[c], ps);
            atomicAdd(&sred[DD + c], ps2);
        }
        __syncthreads();
        atomicAdd(&bnsums[t], sred[t]);
    } else {
        float scv[8], shv[8], bbv[8];
#pragma unroll
        for (int n = 0; n < 8; ++n) {
            const int c = n * 16 + lc;
            scv[n] = ss[c]; shv[n] = ss[DD + c]; bbv[n] = bres[c];
        }
#pragma unroll
        for (int m = 0; m < 2; ++m)
#pragma unroll
            for (int n = 0; n < 8; ++n) {
                const int c = n * 16 + lc;
#pragma unroll
                for (int j = 0; j < 4; ++j) {
                    const size_t r = row0 + w * 32 + m * 16 + lr * 4 + j;
                    const float cv = conv[r * DD + c];
                    const float v = fmaxf(cv * scv[n] + shv[n], 0.0f) + acc[m][n][j] + bbv[n];
                    outb[r * DD + c] = f2bf(v);
                    if (MODE == 3) outf[r * DD + c] = v;
                }
            }
    }
}

// ---------------- CSR aggregate (bf16 gather, 8-wide MLP) --------------------
// aggb[n] = bf16( dinv[n]^2*hb[n] + sum_e dinv[n]dinv[s]*hb[s] )
__global__ __launch_bounds__(256) void k_aggregate(const int* __restrict__ row,
                                                   const int* __restrict__ ssrc,
                                                   const float* __restrict__ dinv,
                                                   const uint* __restrict__ hb,
                                                   uint* __restrict__ aggb) {
    const int n = blockIdx.x * 4 + (threadIdx.x >> 6);
    const int l = threadIdx.x & 63;
    const float dn = dinv[n];
    const uint u = hb[((uint)n << 6) + l];
    const float dn2 = dn * dn;
    float2 acc = make_float2(bflo(u) * dn2, bfhi(u) * dn2);
    const int e0 = row[n], e1 = row[n + 1];
    for (int base = e0; base < e1; base += 64) {
        const int cnt = min(64, e1 - base);
        int sv = 0; float dv = 0.0f;
        if (l < cnt) { sv = ssrc[base + l]; dv = dinv[sv] * dn; }
        for (int i = 0; i < cnt; i += 8) {
            uint vv[8]; float nm[8];
#pragma unroll
            for (int j = 0; j < 8; ++j) {
                const int s = __shfl(sv, i + j);     // pad lanes: s=0, nm=0
                nm[j] = __shfl(dv, i + j);
                vv[j] = hb[((uint)s << 6) + l];
            }
#pragma unroll
            for (int j = 0; j < 8; ++j) {
                acc.x += nm[j] * bflo(vv[j]);
                acc.y += nm[j] * bfhi(vv[j]);
            }
        }
    }
    aggb[((uint)n << 6) + l] = (uint)f2bf(acc.x) | ((uint)f2bf(acc.y) << 16);
}

// ---------------- BN finalize ----------------
__global__ void k_bnfin(const float* __restrict__ sums,
                        const float* __restrict__ gamma,
                        const float* __restrict__ beta,
                        float* __restrict__ ss) {
    int c = threadIdx.x;
    const float invN = 1.0f / (float)NN;
    float mean = sums[c] * invN;
    float var = sums[DD + c] * invN - mean * mean;
    float sc = gamma[c] * rsqrtf(var + 1e-5f);
    ss[c] = sc;
    ss[DD + c] = beta[c] - mean * sc;
}

// ---------------- launch ----------------
extern "C" void kernel_launch(void* const* d_in, const int* in_sizes, int n_in,
                              void* d_out, int out_size, void* d_ws, size_t ws_size,
                              hipStream_t stream) {
    const float* x      = (const float*)d_in[0];
    const int*   ei     = (const int*)d_in[1];
    const float* W_init = (const float*)d_in[3];
    const float* W_gcn  = (const float*)d_in[4];
    const float* gamma  = (const float*)d_in[6];
    const float* beta   = (const float*)d_in[7];
    const float* W_res  = (const float*)d_in[8];
    const float* b_res  = (const float*)d_in[9];

    float* h = (float*)d_out;
    char* p = (char*)d_ws;
    ushort* aggb = (ushort*)p;           p += (size_t)NN * DD * 2;   // 32MB
    ushort* hb  = (ushort*)p;            p += (size_t)NN * DD * 2;   // 32MB
    float*  conv = (float*)p;            p += (size_t)NN * DD * 4;   // 64MB
    uint*   xb   = (uint*)conv;          // aliases conv: dead before first conv write
    float*  dinv = (float*)p;            p += (size_t)NN * 4;
    float*  bns  = (float*)p;            p += 768 * 4;
    float*  ss   = (float*)p;            p += 256 * 4;
    ushort* wt   = (ushort*)p;           p += 7 * 16384 * 2;
    int* blockHist = (int*)p;            p += (size_t)NB * NB * 4;
    int* bstart  = (int*)p;              p += (NB + 1) * 4 + 4;
    uint* packed = (uint*)p;             p += (size_t)NE * 4;
    int* rowp    = (int*)p;              p += ((size_t)NN + 1) * 4 + 4;
    int* ssrc    = (int*)p;

    const int* srcp = ei;
    const int* tgtp = ei + NE;

    k_zero<<<3, 256, 0, stream>>>(bns);
    kA_count<<<NB, 256, 0, stream>>>(tgtp, blockHist);
    kA_scan<<<1, 256, 0, stream>>>(blockHist, bstart);
    kA_scatter<<<NB, 256, 0, stream>>>(srcp, tgtp, blockHist, packed);
    kB_sort<<<NB, 256, 0, stream>>>(packed, bstart, rowp, dinv, ssrc);

    k_prepw<<<7 * 16384 / 256, 256, 0, stream>>>(W_init, W_gcn, W_res, wt);
    k_convx<<<NN * 64 / 256, 256, 0, stream>>>(x, xb);

    k_mgemm<0><<<NN / 128, 256, 0, stream>>>((const ushort*)xb, wt, hb,
                                             nullptr, nullptr, nullptr, nullptr, nullptr);

    for (int i = 0; i < LL; ++i) {
        k_aggregate<<<NN / 4, 256, 0, stream>>>(rowp, ssrc, dinv,
                                                (const uint*)hb, (uint*)aggb);
        k_mgemm<1><<<NN / 128, 256, 0, stream>>>(aggb, wt + (size_t)(1 + i) * 16384,
                                                 nullptr, conv, nullptr, nullptr,
                                                 nullptr, bns + i * 256);
        k_bnfin<<<1, 128, 0, stream>>>(bns + i * 256, gamma + i * DD,
                                       beta + i * DD, ss);
        if (i < LL - 1)
            k_mgemm<2><<<NN / 128, 256, 0, stream>>>(hb, wt + (size_t)(4 + i) * 16384,
                                                     hb, nullptr, conv, ss,
                                                     b_res + i * DD, nullptr);
        else
            k_mgemm<3><<<NN / 128, 256, 0, stream>>>(hb, wt + (size_t)(4 + i) * 16384,
                                                     hb, h, conv, ss,
                                                     b_res + i * DD, nullptr);
    }
}